// Round 9
// baseline (249.059 us; speedup 1.0000x reference)
//
#include <hip/hip_runtime.h>

#define N_NODES 50000
#define N_EDGES 800000
#define D 64
#define N_LAYERS 3
#define N_GRAPHS 512

#define NB 196            // buckets = ceil(50000/256); bucket = dst >> 8
#define BCAP 5120         // per-bucket capacity: mean 4082, sigma 64 -> 16 sigma
#define P3_CHUNK 2048
#define N_P3_WG ((N_EDGES + P3_CHUNK - 1) / P3_CHUNK)  // 391

#define HWS_F4 ((size_t)N_NODES * D / 4)  // 800000 float4 elements in hWs

// ---- CSR build: two-level counting sort ---------------------------------

__global__ __launch_bounds__(256) void bucket_scatter_kernel(
    const int* __restrict__ src, const int* __restrict__ dst,
    int* __restrict__ bucket_fill, int* __restrict__ bucketArr, int nE) {
    __shared__ int hist[NB], base[NB], cur[NB];
    int tid = threadIdx.x;
    if (tid < NB) hist[tid] = 0;
    __syncthreads();
    int s8[8], d8[8];
    bool v8[8];
    int ebase = blockIdx.x * P3_CHUNK + tid;
    #pragma unroll
    for (int i = 0; i < 8; ++i) {
        int e = ebase + i * 256;
        v8[i] = (e < nE);
        if (v8[i]) {
            s8[i] = src[e];
            d8[i] = dst[e];
            atomicAdd(&hist[d8[i] >> 8], 1);
        }
    }
    __syncthreads();
    if (tid < NB) {
        base[tid] = atomicAdd(&bucket_fill[tid], hist[tid]);
        cur[tid] = 0;
    }
    __syncthreads();
    #pragma unroll
    for (int i = 0; i < 8; ++i) {
        if (v8[i]) {
            int b = d8[i] >> 8;
            int r = atomicAdd(&cur[b], 1);
            int pos = base[b] + r;
            if (pos < BCAP)
                bucketArr[b * BCAP + pos] = (s8[i] & 0xFFFF) | ((d8[i] & 0xFF) << 16);
        }
    }
}

__global__ __launch_bounds__(256) void bucket_scan_kernel(
    const int* __restrict__ bucket_fill, int* __restrict__ bucket_base,
    int* __restrict__ offsets) {
    __shared__ int sm[256];
    int tid = threadIdx.x;
    int own = (tid < NB) ? bucket_fill[tid] : 0;
    sm[tid] = own;
    __syncthreads();
    for (int off = 1; off < 256; off <<= 1) {
        int v = (tid >= off) ? sm[tid - off] : 0;
        __syncthreads();
        sm[tid] += v;
        __syncthreads();
    }
    if (tid < NB) bucket_base[tid] = sm[tid] - own;  // exclusive
    if (tid == 0) offsets[N_NODES] = N_EDGES;
}

__global__ __launch_bounds__(256) void bucket_csr_kernel(
    const int* __restrict__ bucket_fill, const int* __restrict__ bucket_base,
    const int* __restrict__ bucketArr,
    int* __restrict__ offsets, int* __restrict__ csr_src,
    float* __restrict__ dinv) {
    __shared__ int ldeg[256], lsc[256], lcur[256];
    int b = blockIdx.x;
    int tid = threadIdx.x;
    int cnt = min(bucket_fill[b], BCAP);
    int cbase = bucket_base[b];
    const int* seg = bucketArr + b * BCAP;
    ldeg[tid] = 0;
    __syncthreads();
    for (int e = tid; e < cnt; e += 256)
        atomicAdd(&ldeg[(seg[e] >> 16) & 0xFF], 1);
    __syncthreads();
    int own = ldeg[tid];
    lsc[tid] = own;
    __syncthreads();
    for (int off = 1; off < 256; off <<= 1) {
        int v = (tid >= off) ? lsc[tid - off] : 0;
        __syncthreads();
        lsc[tid] += v;
        __syncthreads();
    }
    int excl = lsc[tid] - own;
    int node = b * 256 + tid;
    if (node < N_NODES) {
        offsets[node] = cbase + excl;
        dinv[node] = rsqrtf((float)own + 1.0f);
    }
    lcur[tid] = cbase + excl;
    __syncthreads();
    for (int e = tid; e < cnt; e += 256) {
        int p = seg[e];
        int pos = atomicAdd(&lcur[(p >> 16) & 0xFF], 1);
        csr_src[pos] = p & 0xFFFF;
    }
}

// ---- graph boundaries from sorted batch ----------------------------------

__global__ __launch_bounds__(256) void gbounds_kernel(
    const int* __restrict__ batch, int* __restrict__ gstart, int nN) {
    int i = blockIdx.x * 256 + threadIdx.x;
    if (i >= nN) return;
    int b = batch[i];
    int prev = (i == 0) ? -1 : batch[i - 1];
    for (int g = prev + 1; g <= b; ++g) gstart[g] = i;
    if (i == nN - 1) {
        for (int g = b + 1; g <= N_GRAPHS; ++g) gstart[g] = nN;
    }
}

// ---- per-layer kernels --------------------------------------------------

#define GROWS 64
#define LPAD 68
__global__ __launch_bounds__(256) void gemm_kernel(
    const float* __restrict__ h, const float* __restrict__ W,
    const float* __restrict__ dinv, float* __restrict__ hWs, int nN) {
    __shared__ float hs[GROWS][LPAD];
    __shared__ float Wl[D][LPAD];
    int tid = threadIdx.x;
    int row0 = blockIdx.x * GROWS;
    #pragma unroll
    for (int i = 0; i < 4; ++i) {
        int idx4 = tid + i * 256;
        int r = idx4 >> 4;
        int c4 = (idx4 & 15) << 2;
        *(float4*)&Wl[r][c4] = *(const float4*)&W[r * D + c4];
        float4 hv = make_float4(0.f, 0.f, 0.f, 0.f);
        int gr = row0 + r;
        if (gr < nN) hv = *(const float4*)&h[(size_t)gr * D + c4];
        *(float4*)&hs[r][c4] = hv;
    }
    __syncthreads();
    int r0 = (tid >> 4) << 2;
    int c0 = (tid & 15) << 2;
    float acc[4][4];
    #pragma unroll
    for (int i = 0; i < 4; ++i)
        #pragma unroll
        for (int j = 0; j < 4; ++j) acc[i][j] = 0.f;
    #pragma unroll
    for (int kk = 0; kk < D; kk += 4) {
        float4 a0 = *(float4*)&hs[r0 + 0][kk];
        float4 a1 = *(float4*)&hs[r0 + 1][kk];
        float4 a2 = *(float4*)&hs[r0 + 2][kk];
        float4 a3 = *(float4*)&hs[r0 + 3][kk];
        float4 w0 = *(float4*)&Wl[kk + 0][c0];
        float4 w1 = *(float4*)&Wl[kk + 1][c0];
        float4 w2 = *(float4*)&Wl[kk + 2][c0];
        float4 w3 = *(float4*)&Wl[kk + 3][c0];
        float* w0p = &w0.x; float* w1p = &w1.x; float* w2p = &w2.x; float* w3p = &w3.x;
        float4 av[4] = {a0, a1, a2, a3};
        #pragma unroll
        for (int i = 0; i < 4; ++i) {
            #pragma unroll
            for (int j = 0; j < 4; ++j) {
                acc[i][j] += av[i].x * w0p[j] + av[i].y * w1p[j]
                           + av[i].z * w2p[j] + av[i].w * w3p[j];
            }
        }
    }
    #pragma unroll
    for (int i = 0; i < 4; ++i) {
        int gr = row0 + r0 + i;
        if (gr < nN) {
            float s = dinv[gr];
            float4 o = make_float4(acc[i][0] * s, acc[i][1] * s,
                                   acc[i][2] * s, acc[i][3] * s);
            *(float4*)&hWs[(size_t)gr * D + c0] = o;
        }
    }
}

// h_out[t] = dinv[t] * (hWs[t] + sum_{s in N(t)} hWs[s]) + b
// one wave per dst node; 16 lanes per edge (float4 gather).
// L2-warm preamble: each block streams an 8KB chunk of hWs so the
// compulsory per-XCD fill happens at streaming rate, not random-miss rate.
__global__ __launch_bounds__(256) void agg_kernel(
    const int* __restrict__ offsets, const int* __restrict__ csr_src,
    const float* __restrict__ hWs, const float* __restrict__ dinv,
    const float* __restrict__ b, float* __restrict__ hout, int nN) {
    // ---- warm: blocks round-robin XCDs, so chunk = blockIdx.x >> 3 gives
    // each XCD's block-set coverage of the full 12.8 MB replica.
    const float4* hws4 = (const float4*)hWs;
    size_t wbase = ((size_t)(blockIdx.x >> 3) * 512) + threadIdx.x;
    float4 wv0 = make_float4(0.f, 0.f, 0.f, 0.f);
    float4 wv1 = make_float4(0.f, 0.f, 0.f, 0.f);
    if (wbase < HWS_F4) wv0 = hws4[wbase];
    if (wbase + 256 < HWS_F4) wv1 = hws4[wbase + 256];

    int wave = threadIdx.x >> 6;
    int lane = threadIdx.x & 63;
    int t = blockIdx.x * 4 + wave;
    if (t < nN) {
        int beg = offsets[t];
        int end = offsets[t + 1];
        int grp = lane >> 4;          // edge slot 0..3
        int q4  = (lane & 15) << 2;   // dim offset
        float4 a0 = make_float4(0.f, 0.f, 0.f, 0.f);
        float4 a1 = make_float4(0.f, 0.f, 0.f, 0.f);
        int e = beg + grp;
        for (; e + 4 < end; e += 8) {
            int s0 = csr_src[e];
            int s1 = csr_src[e + 4];
            float4 v0 = *(const float4*)&hWs[(size_t)s0 * D + q4];
            float4 v1 = *(const float4*)&hWs[(size_t)s1 * D + q4];
            a0.x += v0.x; a0.y += v0.y; a0.z += v0.z; a0.w += v0.w;
            a1.x += v1.x; a1.y += v1.y; a1.z += v1.z; a1.w += v1.w;
        }
        if (e < end) {
            int s0 = csr_src[e];
            float4 v0 = *(const float4*)&hWs[(size_t)s0 * D + q4];
            a0.x += v0.x; a0.y += v0.y; a0.z += v0.z; a0.w += v0.w;
        }
        float4 acc = make_float4(a0.x + a1.x, a0.y + a1.y,
                                 a0.z + a1.z, a0.w + a1.w);
        #pragma unroll
        for (int m = 16; m < 64; m <<= 1) {
            acc.x += __shfl_xor(acc.x, m);
            acc.y += __shfl_xor(acc.y, m);
            acc.z += __shfl_xor(acc.z, m);
            acc.w += __shfl_xor(acc.w, m);
        }
        if (grp == 0) {
            float4 self = *(const float4*)&hWs[(size_t)t * D + q4];
            float dt = dinv[t];
            float4 bb = *(const float4*)&b[q4];
            float4 o;
            o.x = (acc.x + self.x) * dt + bb.x;
            o.y = (acc.y + self.y) * dt + bb.y;
            o.z = (acc.z + self.z) * dt + bb.z;
            o.w = (acc.w + self.w) * dt + bb.w;
            *(float4*)&hout[(size_t)t * D + q4] = o;
        }
    }
    // keep the warm loads alive (no store, no arithmetic visible to output)
    float wsum = wv0.x + wv0.y + wv0.z + wv0.w + wv1.x + wv1.y + wv1.z + wv1.w;
    asm volatile("" :: "v"(wsum));
}

// ---- pooling: one block per graph, 4 waves, LDS reduce -------------------

__global__ __launch_bounds__(256) void pool_kernel(
    const float* __restrict__ h, const int* __restrict__ gstart,
    float* __restrict__ out) {
    __shared__ float sm[4][D];
    int g = blockIdx.x;
    int wave = threadIdx.x >> 6;
    int lane = threadIdx.x & 63;
    int beg = gstart[g];
    int end = gstart[g + 1];
    float acc = 0.f;
    int n = beg + wave;
    for (; n + 12 < end; n += 16) {
        float a0 = h[(size_t)(n)      * D + lane];
        float a1 = h[(size_t)(n + 4)  * D + lane];
        float a2 = h[(size_t)(n + 8)  * D + lane];
        float a3 = h[(size_t)(n + 12) * D + lane];
        acc += a0 + a1 + a2 + a3;
    }
    for (; n < end; n += 4)
        acc += h[(size_t)n * D + lane];
    sm[wave][lane] = acc;
    __syncthreads();
    if (wave == 0) {
        float s = sm[0][lane] + sm[1][lane] + sm[2][lane] + sm[3][lane];
        float cnt = (float)(end - beg);
        out[g * D + lane] = s / fmaxf(cnt, 1.0f);
    }
}

// ---- launch --------------------------------------------------------------

#define WS_ALIGN(p) ((char*)(((size_t)(p) + 255) & ~(size_t)255))

extern "C" void kernel_launch(void* const* d_in, const int* in_sizes, int n_in,
                              void* d_out, int out_size, void* d_ws, size_t ws_size,
                              hipStream_t stream) {
    const float* x     = (const float*)d_in[0];
    const float* Ws    = (const float*)d_in[1];
    const float* bs    = (const float*)d_in[2];
    const int*   edge  = (const int*)d_in[3];
    const int*   batch = (const int*)d_in[4];
    const int* src = edge;            // edge_index[0]
    const int* dst = edge + N_EDGES;  // edge_index[1]
    float* out = (float*)d_out;

    char* p = (char*)d_ws;
    int* offsets     = (int*)p;      p = WS_ALIGN(p + sizeof(int) * (N_NODES + 1));
    int* csr_src     = (int*)p;      p = WS_ALIGN(p + sizeof(int) * N_EDGES);
    int* bucket_fill = (int*)p;      p = WS_ALIGN(p + sizeof(int) * NB);
    int* bucket_base = (int*)p;      p = WS_ALIGN(p + sizeof(int) * NB);
    int* gstart      = (int*)p;      p = WS_ALIGN(p + sizeof(int) * (N_GRAPHS + 1));
    float* dinv      = (float*)p;    p = WS_ALIGN(p + sizeof(float) * N_NODES);
    float* B1        = (float*)p;    p = WS_ALIGN(p + sizeof(float) * (size_t)N_NODES * D);
    float* B2        = (float*)p;
    // bucketArr (NB*BCAP ints = 4.0 MB) overlays B2: dead before first agg write
    int* bucketArr = (int*)B2;

    hipMemsetAsync(bucket_fill, 0, NB * sizeof(int), stream);

    bucket_scatter_kernel<<<N_P3_WG, 256, 0, stream>>>(src, dst, bucket_fill, bucketArr, N_EDGES);
    bucket_scan_kernel<<<1, 256, 0, stream>>>(bucket_fill, bucket_base, offsets);
    bucket_csr_kernel<<<NB, 256, 0, stream>>>(bucket_fill, bucket_base, bucketArr,
                                              offsets, csr_src, dinv);
    gbounds_kernel<<<(N_NODES + 255) / 256, 256, 0, stream>>>(batch, gstart, N_NODES);

    const float* h = x;
    for (int l = 0; l < N_LAYERS; ++l) {
        gemm_kernel<<<(N_NODES + GROWS - 1) / GROWS, 256, 0, stream>>>(
            h, Ws + (size_t)l * D * D, dinv, B1, N_NODES);
        agg_kernel<<<(N_NODES + 3) / 4, 256, 0, stream>>>(
            offsets, csr_src, B1, dinv, bs + (size_t)l * D, B2, N_NODES);
        h = B2;
    }

    pool_kernel<<<N_GRAPHS, 256, 0, stream>>>(h, gstart, out);
}

// Round 10
// 221.745 us; speedup vs baseline: 1.1232x; 1.1232x over previous
//
#include <hip/hip_runtime.h>

#define N_NODES 50000
#define N_EDGES 800000
#define D 64
#define N_LAYERS 3
#define N_GRAPHS 512

#define NB 196            // buckets = ceil(50000/256); bucket = dst >> 8
#define BCAP 5120         // per-bucket capacity: mean 4082, sigma 64 -> 16 sigma
#define P3_CHUNK 2048
#define N_P3_WG ((N_EDGES + P3_CHUNK - 1) / P3_CHUNK)  // 391

// ---- graph boundaries from sorted batch + zero bucket_fill ---------------
// runs FIRST: removes the hipMemsetAsync dispatch
__global__ __launch_bounds__(256) void gbounds_kernel(
    const int* __restrict__ batch, int* __restrict__ gstart,
    int* __restrict__ bucket_fill, int nN) {
    int i = blockIdx.x * 256 + threadIdx.x;
    if (blockIdx.x == 0 && threadIdx.x < NB) bucket_fill[threadIdx.x] = 0;
    if (i >= nN) return;
    int b = batch[i];
    int prev = (i == 0) ? -1 : batch[i - 1];
    for (int g = prev + 1; g <= b; ++g) gstart[g] = i;
    if (i == nN - 1) {
        for (int g = b + 1; g <= N_GRAPHS; ++g) gstart[g] = nN;
    }
}

// ---- CSR build: two-level counting sort ---------------------------------

// pass 1: bucket edges. LDS histogram -> one global atomic per (WG,bucket),
// then place packed (src | dst_low<<16) into bucket segments.
__global__ __launch_bounds__(256) void bucket_scatter_kernel(
    const int* __restrict__ src, const int* __restrict__ dst,
    int* __restrict__ bucket_fill, int* __restrict__ bucketArr, int nE) {
    __shared__ int hist[NB], base[NB], cur[NB];
    int tid = threadIdx.x;
    if (tid < NB) hist[tid] = 0;
    __syncthreads();
    int s8[8], d8[8];
    bool v8[8];
    int ebase = blockIdx.x * P3_CHUNK + tid;
    #pragma unroll
    for (int i = 0; i < 8; ++i) {
        int e = ebase + i * 256;
        v8[i] = (e < nE);
        if (v8[i]) {
            s8[i] = src[e];
            d8[i] = dst[e];
            atomicAdd(&hist[d8[i] >> 8], 1);
        }
    }
    __syncthreads();
    if (tid < NB) {
        base[tid] = atomicAdd(&bucket_fill[tid], hist[tid]);
        cur[tid] = 0;
    }
    __syncthreads();
    #pragma unroll
    for (int i = 0; i < 8; ++i) {
        if (v8[i]) {
            int b = d8[i] >> 8;
            int r = atomicAdd(&cur[b], 1);
            int pos = base[b] + r;
            if (pos < BCAP)
                bucketArr[b * BCAP + pos] = (s8[i] & 0xFFFF) | ((d8[i] & 0xFF) << 16);
        }
    }
}

// pass 2: per-bucket local counting sort -> offsets, dinv, csr_src.
// Each block redundantly scans the 196 bucket counts in LDS (replaces the
// dedicated bucket_scan dispatch).
__global__ __launch_bounds__(256) void bucket_csr_kernel(
    const int* __restrict__ bucket_fill, const int* __restrict__ bucketArr,
    int* __restrict__ offsets, int* __restrict__ csr_src,
    float* __restrict__ dinv) {
    __shared__ int bsum[256];
    __shared__ int ldeg[256], lsc[256], lcur[256];
    int b = blockIdx.x;
    int tid = threadIdx.x;
    // redundant per-block scan of bucket_fill -> this bucket's CSR base
    int ownb = (tid < NB) ? bucket_fill[tid] : 0;
    bsum[tid] = ownb;
    __syncthreads();
    for (int off = 1; off < 256; off <<= 1) {
        int v = (tid >= off) ? bsum[tid - off] : 0;
        __syncthreads();
        bsum[tid] += v;
        __syncthreads();
    }
    int cbase = (b == 0) ? 0 : bsum[b - 1];
    if (b == NB - 1 && tid == 0) offsets[N_NODES] = bsum[NB - 1];
    int cnt = min(bucket_fill[b], BCAP);
    const int* seg = bucketArr + b * BCAP;
    ldeg[tid] = 0;
    __syncthreads();
    for (int e = tid; e < cnt; e += 256)
        atomicAdd(&ldeg[(seg[e] >> 16) & 0xFF], 1);
    __syncthreads();
    int own = ldeg[tid];
    lsc[tid] = own;
    __syncthreads();
    for (int off = 1; off < 256; off <<= 1) {
        int v = (tid >= off) ? lsc[tid - off] : 0;
        __syncthreads();
        lsc[tid] += v;
        __syncthreads();
    }
    int excl = lsc[tid] - own;
    int node = b * 256 + tid;
    if (node < N_NODES) {
        offsets[node] = cbase + excl;
        dinv[node] = rsqrtf((float)own + 1.0f);
    }
    lcur[tid] = cbase + excl;
    __syncthreads();
    for (int e = tid; e < cnt; e += 256) {
        int p = seg[e];
        int pos = atomicAdd(&lcur[(p >> 16) & 0xFF], 1);
        csr_src[pos] = p & 0xFFFF;
    }
}

// ---- per-layer kernels --------------------------------------------------

#define GROWS 64
#define LPAD 68
__global__ __launch_bounds__(256) void gemm_kernel(
    const float* __restrict__ h, const float* __restrict__ W,
    const float* __restrict__ dinv, float* __restrict__ hWs, int nN) {
    __shared__ float hs[GROWS][LPAD];
    __shared__ float Wl[D][LPAD];
    int tid = threadIdx.x;
    int row0 = blockIdx.x * GROWS;
    #pragma unroll
    for (int i = 0; i < 4; ++i) {
        int idx4 = tid + i * 256;
        int r = idx4 >> 4;
        int c4 = (idx4 & 15) << 2;
        *(float4*)&Wl[r][c4] = *(const float4*)&W[r * D + c4];
        float4 hv = make_float4(0.f, 0.f, 0.f, 0.f);
        int gr = row0 + r;
        if (gr < nN) hv = *(const float4*)&h[(size_t)gr * D + c4];
        *(float4*)&hs[r][c4] = hv;
    }
    __syncthreads();
    int r0 = (tid >> 4) << 2;
    int c0 = (tid & 15) << 2;
    float acc[4][4];
    #pragma unroll
    for (int i = 0; i < 4; ++i)
        #pragma unroll
        for (int j = 0; j < 4; ++j) acc[i][j] = 0.f;
    #pragma unroll
    for (int kk = 0; kk < D; kk += 4) {
        float4 a0 = *(float4*)&hs[r0 + 0][kk];
        float4 a1 = *(float4*)&hs[r0 + 1][kk];
        float4 a2 = *(float4*)&hs[r0 + 2][kk];
        float4 a3 = *(float4*)&hs[r0 + 3][kk];
        float4 w0 = *(float4*)&Wl[kk + 0][c0];
        float4 w1 = *(float4*)&Wl[kk + 1][c0];
        float4 w2 = *(float4*)&Wl[kk + 2][c0];
        float4 w3 = *(float4*)&Wl[kk + 3][c0];
        float* w0p = &w0.x; float* w1p = &w1.x; float* w2p = &w2.x; float* w3p = &w3.x;
        float4 av[4] = {a0, a1, a2, a3};
        #pragma unroll
        for (int i = 0; i < 4; ++i) {
            #pragma unroll
            for (int j = 0; j < 4; ++j) {
                acc[i][j] += av[i].x * w0p[j] + av[i].y * w1p[j]
                           + av[i].z * w2p[j] + av[i].w * w3p[j];
            }
        }
    }
    #pragma unroll
    for (int i = 0; i < 4; ++i) {
        int gr = row0 + r0 + i;
        if (gr < nN) {
            float s = dinv[gr];
            float4 o = make_float4(acc[i][0] * s, acc[i][1] * s,
                                   acc[i][2] * s, acc[i][3] * s);
            *(float4*)&hWs[(size_t)gr * D + c0] = o;
        }
    }
}

// h_out[t] = dinv[t] * (hWs[t] + sum_{s in N(t)} hWs[s]) + b
// one wave per dst node; 16 lanes per edge (float4 gather), 2-deep unroll
__global__ __launch_bounds__(256) void agg_kernel(
    const int* __restrict__ offsets, const int* __restrict__ csr_src,
    const float* __restrict__ hWs, const float* __restrict__ dinv,
    const float* __restrict__ b, float* __restrict__ hout, int nN) {
    int wave = threadIdx.x >> 6;
    int lane = threadIdx.x & 63;
    int t = blockIdx.x * 4 + wave;
    if (t >= nN) return;
    int beg = offsets[t];
    int end = offsets[t + 1];
    int grp = lane >> 4;          // edge slot 0..3
    int q4  = (lane & 15) << 2;   // dim offset
    float4 acc0 = make_float4(0.f, 0.f, 0.f, 0.f);
    float4 acc1 = make_float4(0.f, 0.f, 0.f, 0.f);
    int e = beg + grp;
    for (; e + 4 < end; e += 8) {
        int s0 = csr_src[e];
        int s1 = csr_src[e + 4];
        float4 v0 = *(const float4*)&hWs[(size_t)s0 * D + q4];
        float4 v1 = *(const float4*)&hWs[(size_t)s1 * D + q4];
        acc0.x += v0.x; acc0.y += v0.y; acc0.z += v0.z; acc0.w += v0.w;
        acc1.x += v1.x; acc1.y += v1.y; acc1.z += v1.z; acc1.w += v1.w;
    }
    if (e < end) {
        int s0 = csr_src[e];
        float4 v0 = *(const float4*)&hWs[(size_t)s0 * D + q4];
        acc0.x += v0.x; acc0.y += v0.y; acc0.z += v0.z; acc0.w += v0.w;
    }
    float4 acc = make_float4(acc0.x + acc1.x, acc0.y + acc1.y,
                             acc0.z + acc1.z, acc0.w + acc1.w);
    // fold the 4 edge-slots: lanes {l, l^16, l^32, l^48} share dim-quad
    #pragma unroll
    for (int m = 16; m < 64; m <<= 1) {
        acc.x += __shfl_xor(acc.x, m);
        acc.y += __shfl_xor(acc.y, m);
        acc.z += __shfl_xor(acc.z, m);
        acc.w += __shfl_xor(acc.w, m);
    }
    if (grp == 0) {
        float4 self = *(const float4*)&hWs[(size_t)t * D + q4];
        float dt = dinv[t];
        float4 bb = *(const float4*)&b[q4];
        float4 o;
        o.x = (acc.x + self.x) * dt + bb.x;
        o.y = (acc.y + self.y) * dt + bb.y;
        o.z = (acc.z + self.z) * dt + bb.z;
        o.w = (acc.w + self.w) * dt + bb.w;
        *(float4*)&hout[(size_t)t * D + q4] = o;
    }
}

// ---- pooling: one block per graph, 4 waves, LDS reduce -------------------

__global__ __launch_bounds__(256) void pool_kernel(
    const float* __restrict__ h, const int* __restrict__ gstart,
    float* __restrict__ out) {
    __shared__ float sm[4][D];
    int g = blockIdx.x;
    int wave = threadIdx.x >> 6;
    int lane = threadIdx.x & 63;
    int beg = gstart[g];
    int end = gstart[g + 1];
    float acc = 0.f;
    int n = beg + wave;
    for (; n + 12 < end; n += 16) {
        float a0 = h[(size_t)(n)      * D + lane];
        float a1 = h[(size_t)(n + 4)  * D + lane];
        float a2 = h[(size_t)(n + 8)  * D + lane];
        float a3 = h[(size_t)(n + 12) * D + lane];
        acc += a0 + a1 + a2 + a3;
    }
    for (; n < end; n += 4)
        acc += h[(size_t)n * D + lane];
    sm[wave][lane] = acc;
    __syncthreads();
    if (wave == 0) {
        float s = sm[0][lane] + sm[1][lane] + sm[2][lane] + sm[3][lane];
        float cnt = (float)(end - beg);
        out[g * D + lane] = s / fmaxf(cnt, 1.0f);
    }
}

// ---- launch --------------------------------------------------------------

#define WS_ALIGN(p) ((char*)(((size_t)(p) + 255) & ~(size_t)255))

extern "C" void kernel_launch(void* const* d_in, const int* in_sizes, int n_in,
                              void* d_out, int out_size, void* d_ws, size_t ws_size,
                              hipStream_t stream) {
    const float* x     = (const float*)d_in[0];
    const float* Ws    = (const float*)d_in[1];
    const float* bs    = (const float*)d_in[2];
    const int*   edge  = (const int*)d_in[3];
    const int*   batch = (const int*)d_in[4];
    const int* src = edge;            // edge_index[0]
    const int* dst = edge + N_EDGES;  // edge_index[1]
    float* out = (float*)d_out;

    char* p = (char*)d_ws;
    int* offsets     = (int*)p;      p = WS_ALIGN(p + sizeof(int) * (N_NODES + 1));
    int* csr_src     = (int*)p;      p = WS_ALIGN(p + sizeof(int) * N_EDGES);
    int* bucket_fill = (int*)p;      p = WS_ALIGN(p + sizeof(int) * NB);
    int* gstart      = (int*)p;      p = WS_ALIGN(p + sizeof(int) * (N_GRAPHS + 1));
    float* dinv      = (float*)p;    p = WS_ALIGN(p + sizeof(float) * N_NODES);
    float* B1        = (float*)p;    p = WS_ALIGN(p + sizeof(float) * (size_t)N_NODES * D);
    float* B2        = (float*)p;
    // bucketArr (NB*BCAP ints = 4.0 MB) overlays B2: dead before first agg write
    int* bucketArr = (int*)B2;

    gbounds_kernel<<<(N_NODES + 255) / 256, 256, 0, stream>>>(batch, gstart, bucket_fill, N_NODES);
    bucket_scatter_kernel<<<N_P3_WG, 256, 0, stream>>>(src, dst, bucket_fill, bucketArr, N_EDGES);
    bucket_csr_kernel<<<NB, 256, 0, stream>>>(bucket_fill, bucketArr,
                                              offsets, csr_src, dinv);

    const float* h = x;
    for (int l = 0; l < N_LAYERS; ++l) {
        gemm_kernel<<<(N_NODES + GROWS - 1) / GROWS, 256, 0, stream>>>(
            h, Ws + (size_t)l * D * D, dinv, B1, N_NODES);
        agg_kernel<<<(N_NODES + 3) / 4, 256, 0, stream>>>(
            offsets, csr_src, B1, dinv, bs + (size_t)l * D, B2, N_NODES);
        h = B2;
    }

    pool_kernel<<<N_GRAPHS, 256, 0, stream>>>(h, gstart, out);
}

// Round 11
// 160.100 us; speedup vs baseline: 1.5556x; 1.3850x over previous
//
#include <hip/hip_runtime.h>

#define N_NODES 50000
#define N_EDGES 800000
#define D 64
#define N_LAYERS 3
#define N_GRAPHS 512

#define NB 196            // buckets = ceil(50000/256); bucket = dst >> 8
#define BCAP 5120         // per-bucket capacity: mean 4082, sigma 64 -> 16 sigma
#define P3_CHUNK 2048
#define N_P3_WG ((N_EDGES + P3_CHUNK - 1) / P3_CHUNK)  // 391
#define LPAD 68

// ---- graph boundaries from sorted batch + zero bucket_fill ---------------
__global__ __launch_bounds__(256) void gbounds_kernel(
    const int* __restrict__ batch, int* __restrict__ gstart,
    int* __restrict__ bucket_fill, int nN) {
    int i = blockIdx.x * 256 + threadIdx.x;
    if (blockIdx.x == 0 && threadIdx.x < NB) bucket_fill[threadIdx.x] = 0;
    if (i >= nN) return;
    int b = batch[i];
    int prev = (i == 0) ? -1 : batch[i - 1];
    for (int g = prev + 1; g <= b; ++g) gstart[g] = i;
    if (i == nN - 1) {
        for (int g = b + 1; g <= N_GRAPHS; ++g) gstart[g] = nN;
    }
}

// ---- CSR build: two-level counting sort ---------------------------------

__global__ __launch_bounds__(256) void bucket_scatter_kernel(
    const int* __restrict__ src, const int* __restrict__ dst,
    int* __restrict__ bucket_fill, int* __restrict__ bucketArr, int nE) {
    __shared__ int hist[NB], base[NB], cur[NB];
    int tid = threadIdx.x;
    if (tid < NB) hist[tid] = 0;
    __syncthreads();
    int s8[8], d8[8];
    bool v8[8];
    int ebase = blockIdx.x * P3_CHUNK + tid;
    #pragma unroll
    for (int i = 0; i < 8; ++i) {
        int e = ebase + i * 256;
        v8[i] = (e < nE);
        if (v8[i]) {
            s8[i] = src[e];
            d8[i] = dst[e];
            atomicAdd(&hist[d8[i] >> 8], 1);
        }
    }
    __syncthreads();
    if (tid < NB) {
        base[tid] = atomicAdd(&bucket_fill[tid], hist[tid]);
        cur[tid] = 0;
    }
    __syncthreads();
    #pragma unroll
    for (int i = 0; i < 8; ++i) {
        if (v8[i]) {
            int b = d8[i] >> 8;
            int r = atomicAdd(&cur[b], 1);
            int pos = base[b] + r;
            if (pos < BCAP)
                bucketArr[b * BCAP + pos] = (s8[i] & 0xFFFF) | ((d8[i] & 0xFF) << 16);
        }
    }
}

// pass 2: per-bucket counting sort -> offsets, dinv, csr_src, v0 = x*dinv
__global__ __launch_bounds__(256) void bucket_csr_kernel(
    const int* __restrict__ bucket_fill, const int* __restrict__ bucketArr,
    const float* __restrict__ x,
    int* __restrict__ offsets, int* __restrict__ csr_src,
    float* __restrict__ dinv, float* __restrict__ v0) {
    __shared__ int bsum[256];
    __shared__ int ldeg[256], lsc[256], lcur[256];
    int b = blockIdx.x;
    int tid = threadIdx.x;
    int ownb = (tid < NB) ? bucket_fill[tid] : 0;
    bsum[tid] = ownb;
    __syncthreads();
    for (int off = 1; off < 256; off <<= 1) {
        int v = (tid >= off) ? bsum[tid - off] : 0;
        __syncthreads();
        bsum[tid] += v;
        __syncthreads();
    }
    int cbase = (b == 0) ? 0 : bsum[b - 1];
    if (b == NB - 1 && tid == 0) offsets[N_NODES] = bsum[NB - 1];
    int cnt = min(bucket_fill[b], BCAP);
    const int* seg = bucketArr + b * BCAP;
    ldeg[tid] = 0;
    __syncthreads();
    for (int e = tid; e < cnt; e += 256)
        atomicAdd(&ldeg[(seg[e] >> 16) & 0xFF], 1);
    __syncthreads();
    int own = ldeg[tid];
    lsc[tid] = own;
    __syncthreads();
    for (int off = 1; off < 256; off <<= 1) {
        int v = (tid >= off) ? lsc[tid - off] : 0;
        __syncthreads();
        lsc[tid] += v;
        __syncthreads();
    }
    int excl = lsc[tid] - own;
    int node = b * 256 + tid;
    if (node < N_NODES) {
        float di = rsqrtf((float)own + 1.0f);
        offsets[node] = cbase + excl;
        dinv[node] = di;
        // v0 = x * dinv (layer-0 input in v-space)
        const float4* xr = (const float4*)&x[(size_t)node * D];
        float4* vr = (float4*)&v0[(size_t)node * D];
        #pragma unroll
        for (int i = 0; i < D / 4; ++i) {
            float4 t = xr[i];
            t.x *= di; t.y *= di; t.z *= di; t.w *= di;
            vr[i] = t;
        }
    }
    lcur[tid] = cbase + excl;
    __syncthreads();
    for (int e = tid; e < cnt; e += 256) {
        int p = seg[e];
        int pos = atomicAdd(&lcur[(p >> 16) & 0xFF], 1);
        csr_src[pos] = p & 0xFFFF;
    }
}

// ---- fused layer: gather (h-space) -> LDS -> GEMM -> v_next --------------
// out[t] = [dinv[t]*(sum_{s in N(t)} v[s] + v[t])] @ W + b
// stored as v_next = dinv[t]*out (or out unscaled when last=1)
// block = 256 thr / 4 waves, tile = 16 dst rows; 3125 blocks
__global__ __launch_bounds__(256) void fused_layer_kernel(
    const int* __restrict__ offsets, const int* __restrict__ csr_src,
    const float* __restrict__ v, const float* __restrict__ dinv,
    const float* __restrict__ W, const float* __restrict__ b,
    float* __restrict__ vout, int last) {
    __shared__ float A[16][LPAD];
    __shared__ float Wl[D][LPAD];
    int tid = threadIdx.x;
    // stage W (64x64) cooperatively
    #pragma unroll
    for (int i = 0; i < 4; ++i) {
        int idx4 = tid + i * 256;
        int r = idx4 >> 4;
        int c4 = (idx4 & 15) << 2;
        *(float4*)&Wl[r][c4] = *(const float4*)&W[r * D + c4];
    }
    int wave = tid >> 6;
    int lane = tid & 63;
    int grp = lane >> 4;          // edge slot 0..3
    int q4  = (lane & 15) << 2;   // dim offset
    int t0 = blockIdx.x * 16;
    // gather phase: each wave produces 4 rows of A
    #pragma unroll
    for (int rr = 0; rr < 4; ++rr) {
        int r = rr * 4 + wave;
        int t = t0 + r;
        int beg = offsets[t];
        int end = offsets[t + 1];
        float4 acc0 = make_float4(0.f, 0.f, 0.f, 0.f);
        float4 acc1 = make_float4(0.f, 0.f, 0.f, 0.f);
        int e = beg + grp;
        for (; e + 4 < end; e += 8) {
            int s0 = csr_src[e];
            int s1 = csr_src[e + 4];
            float4 v0 = *(const float4*)&v[(size_t)s0 * D + q4];
            float4 v1 = *(const float4*)&v[(size_t)s1 * D + q4];
            acc0.x += v0.x; acc0.y += v0.y; acc0.z += v0.z; acc0.w += v0.w;
            acc1.x += v1.x; acc1.y += v1.y; acc1.z += v1.z; acc1.w += v1.w;
        }
        if (e < end) {
            int s0 = csr_src[e];
            float4 v0 = *(const float4*)&v[(size_t)s0 * D + q4];
            acc0.x += v0.x; acc0.y += v0.y; acc0.z += v0.z; acc0.w += v0.w;
        }
        float4 acc = make_float4(acc0.x + acc1.x, acc0.y + acc1.y,
                                 acc0.z + acc1.z, acc0.w + acc1.w);
        #pragma unroll
        for (int m = 16; m < 64; m <<= 1) {
            acc.x += __shfl_xor(acc.x, m);
            acc.y += __shfl_xor(acc.y, m);
            acc.z += __shfl_xor(acc.z, m);
            acc.w += __shfl_xor(acc.w, m);
        }
        if (grp == 0) {
            float4 self = *(const float4*)&v[(size_t)t * D + q4];
            float dt = dinv[t];
            float4 a;
            a.x = (acc.x + self.x) * dt;
            a.y = (acc.y + self.y) * dt;
            a.z = (acc.z + self.z) * dt;
            a.w = (acc.w + self.w) * dt;
            *(float4*)&A[r][q4] = a;
        }
    }
    __syncthreads();
    // GEMM phase: 256 threads, each computes 1 row x 1 col-quad of A @ W
    int r  = tid >> 4;
    int c0 = (tid & 15) << 2;
    float4 acc = make_float4(0.f, 0.f, 0.f, 0.f);
    #pragma unroll
    for (int k = 0; k < D; k += 4) {
        float4 a  = *(float4*)&A[r][k];
        float4 w0 = *(float4*)&Wl[k + 0][c0];
        float4 w1 = *(float4*)&Wl[k + 1][c0];
        float4 w2 = *(float4*)&Wl[k + 2][c0];
        float4 w3 = *(float4*)&Wl[k + 3][c0];
        acc.x += a.x * w0.x + a.y * w1.x + a.z * w2.x + a.w * w3.x;
        acc.y += a.x * w0.y + a.y * w1.y + a.z * w2.y + a.w * w3.y;
        acc.z += a.x * w0.z + a.y * w1.z + a.z * w2.z + a.w * w3.z;
        acc.w += a.x * w0.w + a.y * w1.w + a.z * w2.w + a.w * w3.w;
    }
    int t = t0 + r;
    float4 bb = *(const float4*)&b[c0];
    float4 o;
    o.x = acc.x + bb.x;
    o.y = acc.y + bb.y;
    o.z = acc.z + bb.z;
    o.w = acc.w + bb.w;
    if (!last) {
        float dt = dinv[t];
        o.x *= dt; o.y *= dt; o.z *= dt; o.w *= dt;
    }
    *(float4*)&vout[(size_t)t * D + c0] = o;
}

// ---- pooling: one block per graph, 4 waves, LDS reduce -------------------

__global__ __launch_bounds__(256) void pool_kernel(
    const float* __restrict__ h, const int* __restrict__ gstart,
    float* __restrict__ out) {
    __shared__ float sm[4][D];
    int g = blockIdx.x;
    int wave = threadIdx.x >> 6;
    int lane = threadIdx.x & 63;
    int beg = gstart[g];
    int end = gstart[g + 1];
    float acc = 0.f;
    int n = beg + wave;
    for (; n + 12 < end; n += 16) {
        float a0 = h[(size_t)(n)      * D + lane];
        float a1 = h[(size_t)(n + 4)  * D + lane];
        float a2 = h[(size_t)(n + 8)  * D + lane];
        float a3 = h[(size_t)(n + 12) * D + lane];
        acc += a0 + a1 + a2 + a3;
    }
    for (; n < end; n += 4)
        acc += h[(size_t)n * D + lane];
    sm[wave][lane] = acc;
    __syncthreads();
    if (wave == 0) {
        float s = sm[0][lane] + sm[1][lane] + sm[2][lane] + sm[3][lane];
        float cnt = (float)(end - beg);
        out[g * D + lane] = s / fmaxf(cnt, 1.0f);
    }
}

// ---- launch --------------------------------------------------------------

#define WS_ALIGN(p) ((char*)(((size_t)(p) + 255) & ~(size_t)255))

extern "C" void kernel_launch(void* const* d_in, const int* in_sizes, int n_in,
                              void* d_out, int out_size, void* d_ws, size_t ws_size,
                              hipStream_t stream) {
    const float* x     = (const float*)d_in[0];
    const float* Ws    = (const float*)d_in[1];
    const float* bs    = (const float*)d_in[2];
    const int*   edge  = (const int*)d_in[3];
    const int*   batch = (const int*)d_in[4];
    const int* src = edge;            // edge_index[0]
    const int* dst = edge + N_EDGES;  // edge_index[1]
    float* out = (float*)d_out;

    char* p = (char*)d_ws;
    int* offsets     = (int*)p;      p = WS_ALIGN(p + sizeof(int) * (N_NODES + 1));
    int* csr_src     = (int*)p;      p = WS_ALIGN(p + sizeof(int) * N_EDGES);
    int* bucket_fill = (int*)p;      p = WS_ALIGN(p + sizeof(int) * NB);
    int* gstart      = (int*)p;      p = WS_ALIGN(p + sizeof(int) * (N_GRAPHS + 1));
    float* dinv      = (float*)p;    p = WS_ALIGN(p + sizeof(float) * N_NODES);
    float* B1        = (float*)p;    p = WS_ALIGN(p + sizeof(float) * (size_t)N_NODES * D);
    float* B2        = (float*)p;
    // bucketArr (NB*BCAP ints = 4.0 MB) overlays B2: dead before layer-0 write
    int* bucketArr = (int*)B2;

    gbounds_kernel<<<(N_NODES + 255) / 256, 256, 0, stream>>>(batch, gstart, bucket_fill, N_NODES);
    bucket_scatter_kernel<<<N_P3_WG, 256, 0, stream>>>(src, dst, bucket_fill, bucketArr, N_EDGES);
    bucket_csr_kernel<<<NB, 256, 0, stream>>>(bucket_fill, bucketArr, x,
                                              offsets, csr_src, dinv, B1);

    // layer 0: B1(v0) -> B2 ; layer 1: B2 -> B1 ; layer 2 (last): B1 -> B2
    fused_layer_kernel<<<N_NODES / 16, 256, 0, stream>>>(
        offsets, csr_src, B1, dinv, Ws + 0 * (size_t)D * D, bs + 0 * D, B2, 0);
    fused_layer_kernel<<<N_NODES / 16, 256, 0, stream>>>(
        offsets, csr_src, B2, dinv, Ws + 1 * (size_t)D * D, bs + 1 * D, B1, 0);
    fused_layer_kernel<<<N_NODES / 16, 256, 0, stream>>>(
        offsets, csr_src, B1, dinv, Ws + 2 * (size_t)D * D, bs + 2 * D, B2, 1);

    pool_kernel<<<N_GRAPHS, 256, 0, stream>>>(B2, gstart, out);
}